// Round 3
// baseline (712.139 us; speedup 1.0000x reference)
//
#include <hip/hip_runtime.h>

// PMF: out[p] = relu(dot(U[user_ids[p]], V[item_ids[p]])), D=64.
// Round 3: traffic reduction. Pairs are bucketed by uid>>8 (4096 buckets,
// 64KB of user table each) so duplicate-user gathers become L2/LLC hits and
// first-touch gathers get DRAM page locality. Pipeline (all on `stream`):
//   memset(hist) -> hist -> scan -> scatter(uid,iid,pos) -> bucketed dot.
// Falls back to the direct round-2 kernel if ws_size is too small.

constexpr int HIDDEN = 64;
constexpr int K      = 4;     // pairs per 16-lane group
constexpr int NB     = 4096;  // buckets
constexpr int BSHIFT = 8;     // bucket = uid >> 8  (max uid 999,999 -> 3906)

__device__ __forceinline__ float dot16(const float4& a, const float4& b) {
    return a.x * b.x + a.y * b.y + a.z * b.z + a.w * b.w;
}

__global__ __launch_bounds__(256) void hist_kernel(
    const int* __restrict__ user_ids, int* __restrict__ hist, int n)
{
    int p = blockIdx.x * blockDim.x + threadIdx.x;
    if (p < n) atomicAdd(&hist[user_ids[p] >> BSHIFT], 1);
}

__global__ __launch_bounds__(1024) void scan_kernel(
    const int* __restrict__ hist, int* __restrict__ offs)
{
    __shared__ int part[1024];
    const int t = threadIdx.x;
    int4 h = reinterpret_cast<const int4*>(hist)[t];
    int s = h.x + h.y + h.z + h.w;
    part[t] = s;
    __syncthreads();
    #pragma unroll
    for (int d = 1; d < 1024; d <<= 1) {
        int v = (t >= d) ? part[t - d] : 0;
        __syncthreads();
        part[t] += v;
        __syncthreads();
    }
    int excl = part[t] - s;  // exclusive prefix of this thread's 4-chunk
    int4 o;
    o.x = excl;
    o.y = o.x + h.x;
    o.z = o.y + h.y;
    o.w = o.z + h.z;
    reinterpret_cast<int4*>(offs)[t] = o;
}

__global__ __launch_bounds__(256) void scatter_kernel(
    const int* __restrict__ user_ids, const int* __restrict__ item_ids,
    int* __restrict__ offs, int* __restrict__ uid_s, int* __restrict__ iid_s,
    int* __restrict__ pos_s, int n)
{
    int p = blockIdx.x * blockDim.x + threadIdx.x;
    if (p < n) {
        int u = user_ids[p];
        int q = atomicAdd(&offs[u >> BSHIFT], 1);
        uid_s[q] = u;
        iid_s[q] = item_ids[p];
        pos_s[q] = p;
    }
}

__global__ __launch_bounds__(256) void pmf_dot_bucketed(
    const float* __restrict__ user_emb, const float* __restrict__ item_emb,
    const int* __restrict__ uid_s, const int* __restrict__ iid_s,
    const int* __restrict__ pos_s, float* __restrict__ out, int n)
{
    const int group  = (blockIdx.x * blockDim.x + threadIdx.x) >> 4;
    const int lane16 = threadIdx.x & 15;
    const int q0     = group * K;

    if (q0 + K <= n) {
        const int4 u4 = *reinterpret_cast<const int4*>(uid_s + q0);
        const int4 i4 = *reinterpret_cast<const int4*>(iid_s + q0);
        const int4 p4 = *reinterpret_cast<const int4*>(pos_s + q0);

        const float4 a0 = *(reinterpret_cast<const float4*>(user_emb + (size_t)u4.x * HIDDEN) + lane16);
        const float4 a1 = *(reinterpret_cast<const float4*>(user_emb + (size_t)u4.y * HIDDEN) + lane16);
        const float4 a2 = *(reinterpret_cast<const float4*>(user_emb + (size_t)u4.z * HIDDEN) + lane16);
        const float4 a3 = *(reinterpret_cast<const float4*>(user_emb + (size_t)u4.w * HIDDEN) + lane16);
        const float4 b0 = *(reinterpret_cast<const float4*>(item_emb + (size_t)i4.x * HIDDEN) + lane16);
        const float4 b1 = *(reinterpret_cast<const float4*>(item_emb + (size_t)i4.y * HIDDEN) + lane16);
        const float4 b2 = *(reinterpret_cast<const float4*>(item_emb + (size_t)i4.z * HIDDEN) + lane16);
        const float4 b3 = *(reinterpret_cast<const float4*>(item_emb + (size_t)i4.w * HIDDEN) + lane16);

        float d0 = dot16(a0, b0);
        float d1 = dot16(a1, b1);
        float d2 = dot16(a2, b2);
        float d3 = dot16(a3, b3);

        #pragma unroll
        for (int s = 1; s < 16; s <<= 1) {
            d0 += __shfl_xor(d0, s, 16);
            d1 += __shfl_xor(d1, s, 16);
            d2 += __shfl_xor(d2, s, 16);
            d3 += __shfl_xor(d3, s, 16);
        }

        if (lane16 == 0) {
            out[p4.x] = d0 > 0.0f ? d0 : 0.0f;
            out[p4.y] = d1 > 0.0f ? d1 : 0.0f;
            out[p4.z] = d2 > 0.0f ? d2 : 0.0f;
            out[p4.w] = d3 > 0.0f ? d3 : 0.0f;
        }
    } else if (q0 < n) {
        for (int q = q0; q < n; ++q) {
            const int uid = uid_s[q];
            const int iid = iid_s[q];
            const float4 a = *(reinterpret_cast<const float4*>(user_emb + (size_t)uid * HIDDEN) + lane16);
            const float4 b = *(reinterpret_cast<const float4*>(item_emb + (size_t)iid * HIDDEN) + lane16);
            float d = dot16(a, b);
            #pragma unroll
            for (int s = 1; s < 16; s <<= 1) d += __shfl_xor(d, s, 16);
            if (lane16 == 0) out[pos_s[q]] = d > 0.0f ? d : 0.0f;
        }
    }
}

// Direct fallback (round-2 kernel) if ws is too small for bucketing.
__global__ __launch_bounds__(256) void pmf_dot_direct(
    const float* __restrict__ user_emb, const float* __restrict__ item_emb,
    const int* __restrict__ user_ids, const int* __restrict__ item_ids,
    float* __restrict__ out, int n)
{
    const int group  = (blockIdx.x * blockDim.x + threadIdx.x) >> 4;
    const int lane16 = threadIdx.x & 15;
    const int p0     = group * K;

    if (p0 + K <= n) {
        const int4 u4 = *reinterpret_cast<const int4*>(user_ids + p0);
        const int4 i4 = *reinterpret_cast<const int4*>(item_ids + p0);
        const float4 a0 = *(reinterpret_cast<const float4*>(user_emb + (size_t)u4.x * HIDDEN) + lane16);
        const float4 a1 = *(reinterpret_cast<const float4*>(user_emb + (size_t)u4.y * HIDDEN) + lane16);
        const float4 a2 = *(reinterpret_cast<const float4*>(user_emb + (size_t)u4.z * HIDDEN) + lane16);
        const float4 a3 = *(reinterpret_cast<const float4*>(user_emb + (size_t)u4.w * HIDDEN) + lane16);
        const float4 b0 = *(reinterpret_cast<const float4*>(item_emb + (size_t)i4.x * HIDDEN) + lane16);
        const float4 b1 = *(reinterpret_cast<const float4*>(item_emb + (size_t)i4.y * HIDDEN) + lane16);
        const float4 b2 = *(reinterpret_cast<const float4*>(item_emb + (size_t)i4.z * HIDDEN) + lane16);
        const float4 b3 = *(reinterpret_cast<const float4*>(item_emb + (size_t)i4.w * HIDDEN) + lane16);
        float d0 = dot16(a0, b0), d1 = dot16(a1, b1), d2 = dot16(a2, b2), d3 = dot16(a3, b3);
        #pragma unroll
        for (int s = 1; s < 16; s <<= 1) {
            d0 += __shfl_xor(d0, s, 16);
            d1 += __shfl_xor(d1, s, 16);
            d2 += __shfl_xor(d2, s, 16);
            d3 += __shfl_xor(d3, s, 16);
        }
        if (lane16 == 0) {
            float4 r = { d0 > 0.0f ? d0 : 0.0f, d1 > 0.0f ? d1 : 0.0f,
                         d2 > 0.0f ? d2 : 0.0f, d3 > 0.0f ? d3 : 0.0f };
            *reinterpret_cast<float4*>(out + p0) = r;
        }
    } else if (p0 < n) {
        for (int p = p0; p < n; ++p) {
            const int uid = user_ids[p];
            const int iid = item_ids[p];
            const float4 a = *(reinterpret_cast<const float4*>(user_emb + (size_t)uid * HIDDEN) + lane16);
            const float4 b = *(reinterpret_cast<const float4*>(item_emb + (size_t)iid * HIDDEN) + lane16);
            float d = dot16(a, b);
            #pragma unroll
            for (int s = 1; s < 16; s <<= 1) d += __shfl_xor(d, s, 16);
            if (lane16 == 0) out[p] = d > 0.0f ? d : 0.0f;
        }
    }
}

extern "C" void kernel_launch(void* const* d_in, const int* in_sizes, int n_in,
                              void* d_out, int out_size, void* d_ws, size_t ws_size,
                              hipStream_t stream) {
    const float* user_emb = (const float*)d_in[0];
    const float* item_emb = (const float*)d_in[1];
    const int*   user_ids = (const int*)d_in[2];
    const int*   item_ids = (const int*)d_in[3];
    float* out = (float*)d_out;

    const int n = in_sizes[2];  // 2,000,000 pairs

    // Workspace layout (aligned): hist[NB] | offs[NB] | uid_s[n] | iid_s[n] | pos_s[n]
    const size_t histB = (size_t)NB * 4;
    const size_t base  = 2 * histB;                 // 32 KiB
    const size_t need  = base + 3 * (size_t)n * 4;  // ~24.03 MB

    const int threads = 256;
    const int pairs_per_block = (threads / 16) * K;  // 64
    const int dot_blocks = (n + pairs_per_block - 1) / pairs_per_block;

    if (ws_size >= need) {
        char* ws    = (char*)d_ws;
        int*  hist  = (int*)(ws);
        int*  offs  = (int*)(ws + histB);
        int*  uid_s = (int*)(ws + base);
        int*  iid_s = (int*)(ws + base + (size_t)n * 4);
        int*  pos_s = (int*)(ws + base + 2 * (size_t)n * 4);

        hipMemsetAsync(hist, 0, histB, stream);

        const int lin_blocks = (n + threads - 1) / threads;
        hist_kernel<<<lin_blocks, threads, 0, stream>>>(user_ids, hist, n);
        scan_kernel<<<1, 1024, 0, stream>>>(hist, offs);
        scatter_kernel<<<lin_blocks, threads, 0, stream>>>(
            user_ids, item_ids, offs, uid_s, iid_s, pos_s, n);
        pmf_dot_bucketed<<<dot_blocks, threads, 0, stream>>>(
            user_emb, item_emb, uid_s, iid_s, pos_s, out, n);
    } else {
        pmf_dot_direct<<<dot_blocks, threads, 0, stream>>>(
            user_emb, item_emb, user_ids, item_ids, out, n);
    }
}

// Round 4
// 494.167 us; speedup vs baseline: 1.4411x; 1.4411x over previous
//
#include <hip/hip_runtime.h>
#include <stdint.h>

// PMF: out[p] = relu(dot(U[user_ids[p]], V[item_ids[p]])), D=64.
// Round 4: bucket-partition pairs by uid>>11 (512 buckets) with LDS-aggregated
// histogram/scatter (no deep global atomic chains), pack (uid,iid,pos) into one
// uint64, then run the gather kernel with an XCD-contiguous block swizzle so
// each XCD's L2 captures duplicate-user rows (live window ~1.5MB < 4MB L2).

constexpr int HIDDEN = 64;
constexpr int K      = 4;      // pairs per 16-lane group in dot kernel
constexpr int NB     = 512;    // buckets
constexpr int BSHIFT = 11;     // bucket = uid >> 11 (max 488)
constexpr int PPB    = 8192;   // pairs per partition block

__device__ __forceinline__ float dot16(const float4& a, const float4& b) {
    return a.x * b.x + a.y * b.y + a.z * b.z + a.w * b.w;
}

__device__ __forceinline__ uint64_t pack_pair(int uid, int iid, int pos) {
    return ((uint64_t)uid << 38) | ((uint64_t)iid << 21) | (uint64_t)pos;
}

__global__ __launch_bounds__(256) void hist_kernel(
    const int* __restrict__ user_ids, int* __restrict__ ghist, int n)
{
    __shared__ int h[NB];
    for (int i = threadIdx.x; i < NB; i += 256) h[i] = 0;
    __syncthreads();
    const int base = blockIdx.x * PPB;
    for (int i = threadIdx.x; i < PPB; i += 256) {
        int p = base + i;
        if (p < n) atomicAdd(&h[user_ids[p] >> BSHIFT], 1);
    }
    __syncthreads();
    for (int i = threadIdx.x; i < NB; i += 256) {
        int c = h[i];
        if (c) atomicAdd(&ghist[i], c);  // <=245 adds per bucket total
    }
}

__global__ __launch_bounds__(512) void scan_kernel(
    const int* __restrict__ ghist, int* __restrict__ cursor)
{
    __shared__ int s[NB];
    const int t = threadIdx.x;
    int v = ghist[t];
    s[t] = v;
    __syncthreads();
    #pragma unroll
    for (int d = 1; d < NB; d <<= 1) {
        int x = (t >= d) ? s[t - d] : 0;
        __syncthreads();
        s[t] += x;
        __syncthreads();
    }
    cursor[t] = s[t] - v;  // exclusive prefix -> running cursor per bucket
}

__global__ __launch_bounds__(256) void scatter_kernel(
    const int* __restrict__ user_ids, const int* __restrict__ item_ids,
    int* __restrict__ cursor, uint64_t* __restrict__ sorted, int n)
{
    __shared__ int h[NB];
    __shared__ int gbase[NB];
    for (int i = threadIdx.x; i < NB; i += 256) h[i] = 0;
    __syncthreads();
    const int base = blockIdx.x * PPB;
    // pass 1: local bucket counts (LDS atomics, ~16 deep per bucket)
    for (int i = threadIdx.x; i < PPB; i += 256) {
        int p = base + i;
        if (p < n) atomicAdd(&h[user_ids[p] >> BSHIFT], 1);
    }
    __syncthreads();
    // reserve global space: ONE global atomic per (block,bucket)
    for (int i = threadIdx.x; i < NB; i += 256) {
        int c = h[i];
        gbase[i] = c ? atomicAdd(&cursor[i], c) : 0;
    }
    __syncthreads();
    for (int i = threadIdx.x; i < NB; i += 256) h[i] = 0;
    __syncthreads();
    // pass 2: rank locally in LDS, store packed tuple (8B, runs ~16 pairs)
    for (int i = threadIdx.x; i < PPB; i += 256) {
        int p = base + i;
        if (p < n) {
            int u = user_ids[p];
            int b = u >> BSHIFT;
            int r = atomicAdd(&h[b], 1);
            sorted[(size_t)gbase[b] + r] = pack_pair(u, item_ids[p], p);
        }
    }
}

__global__ __launch_bounds__(256) void pmf_dot_sorted(
    const float* __restrict__ user_emb, const float* __restrict__ item_emb,
    const uint64_t* __restrict__ sorted, float* __restrict__ out,
    int n, int chunk)
{
    // XCD swizzle: HW assigns block b to XCD b%8 (round-robin). Give XCD k the
    // contiguous work range [k*chunk, (k+1)*chunk) so a bucket's duplicate-user
    // gathers all hit the SAME XCD's L2.
    const int b2     = (blockIdx.x & 7) * chunk + (blockIdx.x >> 3);
    const int group  = b2 * 16 + (threadIdx.x >> 4);
    const int lane16 = threadIdx.x & 15;
    const int q0     = group * K;

    if (q0 + K <= n) {
        const ulonglong2 v01 = *reinterpret_cast<const ulonglong2*>(sorted + q0);
        const ulonglong2 v23 = *reinterpret_cast<const ulonglong2*>(sorted + q0 + 2);
        const uint64_t v0 = v01.x, v1 = v01.y, v2 = v23.x, v3 = v23.y;

        const int u0 = (int)(v0 >> 38), i0 = (int)((v0 >> 21) & 0x1FFFF), p0 = (int)(v0 & 0x1FFFFF);
        const int u1 = (int)(v1 >> 38), i1 = (int)((v1 >> 21) & 0x1FFFF), p1 = (int)(v1 & 0x1FFFFF);
        const int u2 = (int)(v2 >> 38), i2 = (int)((v2 >> 21) & 0x1FFFF), p2 = (int)(v2 & 0x1FFFFF);
        const int u3 = (int)(v3 >> 38), i3 = (int)((v3 >> 21) & 0x1FFFF), p3 = (int)(v3 & 0x1FFFFF);

        const float4 a0 = *(reinterpret_cast<const float4*>(user_emb + (size_t)u0 * HIDDEN) + lane16);
        const float4 a1 = *(reinterpret_cast<const float4*>(user_emb + (size_t)u1 * HIDDEN) + lane16);
        const float4 a2 = *(reinterpret_cast<const float4*>(user_emb + (size_t)u2 * HIDDEN) + lane16);
        const float4 a3 = *(reinterpret_cast<const float4*>(user_emb + (size_t)u3 * HIDDEN) + lane16);
        const float4 b0 = *(reinterpret_cast<const float4*>(item_emb + (size_t)i0 * HIDDEN) + lane16);
        const float4 b1 = *(reinterpret_cast<const float4*>(item_emb + (size_t)i1 * HIDDEN) + lane16);
        const float4 b2v = *(reinterpret_cast<const float4*>(item_emb + (size_t)i2 * HIDDEN) + lane16);
        const float4 b3 = *(reinterpret_cast<const float4*>(item_emb + (size_t)i3 * HIDDEN) + lane16);

        float d0 = dot16(a0, b0);
        float d1 = dot16(a1, b1);
        float d2 = dot16(a2, b2v);
        float d3 = dot16(a3, b3);

        #pragma unroll
        for (int s = 1; s < 16; s <<= 1) {
            d0 += __shfl_xor(d0, s, 16);
            d1 += __shfl_xor(d1, s, 16);
            d2 += __shfl_xor(d2, s, 16);
            d3 += __shfl_xor(d3, s, 16);
        }

        if (lane16 == 0) {
            out[p0] = d0 > 0.0f ? d0 : 0.0f;
            out[p1] = d1 > 0.0f ? d1 : 0.0f;
            out[p2] = d2 > 0.0f ? d2 : 0.0f;
            out[p3] = d3 > 0.0f ? d3 : 0.0f;
        }
    } else if (q0 < n) {
        for (int q = q0; q < n; ++q) {
            const uint64_t v = sorted[q];
            const int u = (int)(v >> 38), i = (int)((v >> 21) & 0x1FFFF), p = (int)(v & 0x1FFFFF);
            const float4 a = *(reinterpret_cast<const float4*>(user_emb + (size_t)u * HIDDEN) + lane16);
            const float4 b = *(reinterpret_cast<const float4*>(item_emb + (size_t)i * HIDDEN) + lane16);
            float d = dot16(a, b);
            #pragma unroll
            for (int s = 1; s < 16; s <<= 1) d += __shfl_xor(d, s, 16);
            if (lane16 == 0) out[p] = d > 0.0f ? d : 0.0f;
        }
    }
}

// Direct fallback (round-2 kernel) if ws too small.
__global__ __launch_bounds__(256) void pmf_dot_direct(
    const float* __restrict__ user_emb, const float* __restrict__ item_emb,
    const int* __restrict__ user_ids, const int* __restrict__ item_ids,
    float* __restrict__ out, int n)
{
    const int group  = (blockIdx.x * blockDim.x + threadIdx.x) >> 4;
    const int lane16 = threadIdx.x & 15;
    const int p0     = group * K;
    if (p0 + K <= n) {
        const int4 u4 = *reinterpret_cast<const int4*>(user_ids + p0);
        const int4 i4 = *reinterpret_cast<const int4*>(item_ids + p0);
        const float4 a0 = *(reinterpret_cast<const float4*>(user_emb + (size_t)u4.x * HIDDEN) + lane16);
        const float4 a1 = *(reinterpret_cast<const float4*>(user_emb + (size_t)u4.y * HIDDEN) + lane16);
        const float4 a2 = *(reinterpret_cast<const float4*>(user_emb + (size_t)u4.z * HIDDEN) + lane16);
        const float4 a3 = *(reinterpret_cast<const float4*>(user_emb + (size_t)u4.w * HIDDEN) + lane16);
        const float4 b0 = *(reinterpret_cast<const float4*>(item_emb + (size_t)i4.x * HIDDEN) + lane16);
        const float4 b1 = *(reinterpret_cast<const float4*>(item_emb + (size_t)i4.y * HIDDEN) + lane16);
        const float4 b2 = *(reinterpret_cast<const float4*>(item_emb + (size_t)i4.z * HIDDEN) + lane16);
        const float4 b3 = *(reinterpret_cast<const float4*>(item_emb + (size_t)i4.w * HIDDEN) + lane16);
        float d0 = dot16(a0, b0), d1 = dot16(a1, b1), d2 = dot16(a2, b2), d3 = dot16(a3, b3);
        #pragma unroll
        for (int s = 1; s < 16; s <<= 1) {
            d0 += __shfl_xor(d0, s, 16);
            d1 += __shfl_xor(d1, s, 16);
            d2 += __shfl_xor(d2, s, 16);
            d3 += __shfl_xor(d3, s, 16);
        }
        if (lane16 == 0) {
            float4 r = { d0 > 0.0f ? d0 : 0.0f, d1 > 0.0f ? d1 : 0.0f,
                         d2 > 0.0f ? d2 : 0.0f, d3 > 0.0f ? d3 : 0.0f };
            *reinterpret_cast<float4*>(out + p0) = r;
        }
    } else if (p0 < n) {
        for (int p = p0; p < n; ++p) {
            const int uid = user_ids[p];
            const int iid = item_ids[p];
            const float4 a = *(reinterpret_cast<const float4*>(user_emb + (size_t)uid * HIDDEN) + lane16);
            const float4 b = *(reinterpret_cast<const float4*>(item_emb + (size_t)iid * HIDDEN) + lane16);
            float d = dot16(a, b);
            #pragma unroll
            for (int s = 1; s < 16; s <<= 1) d += __shfl_xor(d, s, 16);
            if (lane16 == 0) out[p] = d > 0.0f ? d : 0.0f;
        }
    }
}

extern "C" void kernel_launch(void* const* d_in, const int* in_sizes, int n_in,
                              void* d_out, int out_size, void* d_ws, size_t ws_size,
                              hipStream_t stream) {
    const float* user_emb = (const float*)d_in[0];
    const float* item_emb = (const float*)d_in[1];
    const int*   user_ids = (const int*)d_in[2];
    const int*   item_ids = (const int*)d_in[3];
    float* out = (float*)d_out;

    const int n = in_sizes[2];  // 2,000,000

    // ws layout: ghist[NB] | cursor[NB] | pad | sorted[n] (8B each)
    const size_t sortedOff = 4096;
    const size_t need = sortedOff + (size_t)n * 8;

    const int threads = 256;
    const int pairs_per_dot_block = (threads / 16) * K;  // 64
    int dot_blocks = (n + pairs_per_dot_block - 1) / pairs_per_dot_block;

    if (ws_size >= need) {
        char* ws = (char*)d_ws;
        int*      ghist  = (int*)ws;
        int*      cursor = (int*)(ws + NB * 4);
        uint64_t* sorted = (uint64_t*)(ws + sortedOff);

        hipMemsetAsync(ghist, 0, NB * 4, stream);

        const int part_blocks = (n + PPB - 1) / PPB;  // 245
        hist_kernel<<<part_blocks, threads, 0, stream>>>(user_ids, ghist, n);
        scan_kernel<<<1, NB, 0, stream>>>(ghist, cursor);
        scatter_kernel<<<part_blocks, threads, 0, stream>>>(
            user_ids, item_ids, cursor, sorted, n);

        const int blocks8 = ((dot_blocks + 7) / 8) * 8;
        const int chunk   = blocks8 / 8;
        pmf_dot_sorted<<<blocks8, threads, 0, stream>>>(
            user_emb, item_emb, sorted, out, n, chunk);
    } else {
        pmf_dot_direct<<<dot_blocks, threads, 0, stream>>>(
            user_emb, item_emb, user_ids, item_ids, out, n);
    }
}